// Round 15
// baseline (236.090 us; speedup 1.0000x reference)
//
#include <hip/hip_runtime.h>
#include <hip/hip_bf16.h>
#include <hip/hip_fp16.h>

// GCN2: 3x GCNConv(relu,relu,none) + global_mean_pool + linear head.
// R15 = R14 with a fast fused-y epilogue: W3l staged TRANSPOSED in LDS
// ([19][128], stride 132), GEMV = 16 float4 iters/lane (was 64 scalar,
// 870cyc/wave -> ~300). R14's fusion was neutral because the epilogue's
// serial scalar-LDS loop cost exactly what the deleted launch saved.

#define HIDDEN 128
#define F_IN 11
#define NCLS 19
#define NBITS 8
#define NB 256
#define RNODES 256
#define EPB 4096
#define OUTL_CAP 5376

typedef _Float16 half8 __attribute__((ext_vector_type(8)));
typedef float floatx4 __attribute__((ext_vector_type(4)));

// ---------------- scatter (+ folded w3l / W2 conversion blocks) ----------------

__global__ void scatter_kernel(const int* __restrict__ src, const int* __restrict__ dst,
                               int* __restrict__ bcur, unsigned int* __restrict__ bents,
                               int E, int cap, int nSB,
                               const float* __restrict__ W3, const float* __restrict__ Wl,
                               const float* __restrict__ b3, float* __restrict__ W3l,
                               float* __restrict__ b3l, const float* __restrict__ W2,
                               __half* __restrict__ W2Th) {
    __shared__ int hist[NB];
    __shared__ int binoff[NB];
    __shared__ int runrel[NB];
    __shared__ unsigned int ebuf[EPB];
    __shared__ unsigned short binOf[EPB];
    __shared__ int cw[4];
    int tid = threadIdx.x, lane = tid & 63, w = tid >> 6;

    if (blockIdx.x >= nSB) {                 // ---- folded precompute blocks ----
        int xb = blockIdx.x - nSB;
        if (xb < 11) {
            float* Wls = (float*)ebuf;       // alias: 128*19 floats = 9.7KB
            for (int i = tid; i < HIDDEN * NCLS; i += 256) Wls[i] = Wl[i];
            __syncthreads();
            if (xb < 10) {
                int o = xb * 256 + tid;
                if (o < HIDDEN * NCLS) {
                    int i = o / NCLS, j = o % NCLS;
                    float acc = 0.f;
#pragma unroll 8
                    for (int k = 0; k < HIDDEN; ++k) acc += W3[i * HIDDEN + k] * Wls[k * NCLS + j];
                    W3l[o] = acc;
                }
            } else if (tid < NCLS) {
                float acc = 0.f;
#pragma unroll 8
                for (int k = 0; k < HIDDEN; ++k) acc += b3[k] * Wls[k * NCLS + tid];
                b3l[tid] = acc;
            }
        } else {                              // xb 11..14: W2Th[n][k] = fp16(W2[k][n])
            int base = (xb - 11) * 4096;
#pragma unroll
            for (int r = 0; r < 16; ++r) {
                int idx = base + tid + 256 * r;
                int k = idx >> 7, nn2 = idx & 127;
                W2Th[nn2 * HIDDEN + k] = __float2half(W2[idx]);
            }
        }
        return;
    }

    // ---- scatter proper ----
    int base = blockIdx.x * EPB;
    int cnt = min(EPB, E - base);
    for (int i = tid; i < NB; i += 256) hist[i] = 0;
    __syncthreads();
    unsigned int pk[16];
    int rk[16];
#pragma unroll
    for (int j = 0; j < 16; ++j) {
        int idx = tid + 256 * j;
        if (idx < cnt) {
            int e = base + idx;
            int s = src[e], d = dst[e];
            pk[j] = (unsigned int)s | ((unsigned int)d << 16);
            int bin = d >> NBITS;
            int r = atomicAdd(&hist[bin], 1);
            rk[j] = r | (bin << 16);
        } else rk[j] = -1;
    }
    __syncthreads();
    int v = hist[tid], xv = v;                 // 256 threads scan 256 bins
#pragma unroll
    for (int d = 1; d < 64; d <<= 1) {
        int t = __shfl_up(xv, d, 64);
        if (lane >= d) xv += t;
    }
    if (lane == 63) cw[w] = xv;
    __syncthreads();
    int waveoff = 0;
    for (int wi = 0; wi < w; ++wi) waveoff += cw[wi];
    binoff[tid] = waveoff + xv - v;
    runrel[tid] = v ? atomicAdd(&bcur[tid], v) : 0;
    __syncthreads();
#pragma unroll
    for (int j = 0; j < 16; ++j) {
        if (rk[j] >= 0) {
            int bin = rk[j] >> 16, r = rk[j] & 0xFFFF;
            int pos = binoff[bin] + r;
            ebuf[pos] = pk[j];
            binOf[pos] = (unsigned short)bin;
        }
    }
    __syncthreads();
    for (int i = tid; i < cnt; i += 256) {
        int bin = binOf[i];
        int rel = runrel[bin] + (i - binoff[bin]);
        if (rel < cap)                          // hard guard: never cross regions
            bents[bin * cap + rel] = ebuf[i];
    }
}

// per bucket (256 nodes): counts -> scan -> LDS scatter -> dense writes. 512 threads.
__global__ void build_kernel(const unsigned int* __restrict__ bents, const int* __restrict__ bcur,
                             const float* __restrict__ x, const int* __restrict__ batch,
                             int2* __restrict__ begend, unsigned short* __restrict__ csr16,
                             float* __restrict__ dinv, float* __restrict__ gcnt,
                             __half* __restrict__ x16h, int n, int cap, int rst) {
    __shared__ int counts[RNODES];
    __shared__ int lcur[RNODES];
    __shared__ unsigned short outl[OUTL_CAP];
    __shared__ int wsums[4];
    int tid = threadIdx.x;          // 512
    int lane = tid & 63, w = tid >> 6;
    int b = blockIdx.x;
    int base = b << NBITS;
    int nn = min(RNODES, n - base);
    int ebase = b * cap;
    int ecnt = min(bcur[b], cap);   // hard guard
    int st = b * rst;
    for (int i = tid; i < RNODES; i += 512) counts[i] = 0;
    __syncthreads();
    for (int e = tid; e < ecnt; e += 512)
        atomicAdd(&counts[(bents[ebase + e] >> 16) - base], 1);
    __syncthreads();
    int v = 0, xv = 0;
    if (tid < RNODES) {             // 4 waves scan 256 entries
        v = (tid < nn) ? counts[tid] + 1 : 0;
        xv = v;
#pragma unroll
        for (int d = 1; d < 64; d <<= 1) {
            int t = __shfl_up(xv, d, 64);
            if (lane >= d) xv += t;
        }
        if (lane == 63) wsums[w] = xv;
    }
    __syncthreads();
    if (tid < nn) {
        int waveoff = 0;
        for (int wi = 0; wi < w; ++wi) waveoff += wsums[wi];
        int excl = waveoff + xv - v;
        lcur[tid] = excl + 1;
        outl[excl] = (unsigned short)(base + tid);        // self-loop slot 0
        begend[base + tid] = make_int2(st + excl, st + excl + v);
        atomicAdd(&gcnt[batch[base + tid]], 1.0f);
    }
    __syncthreads();
    for (int e = tid; e < ecnt; e += 512) {
        unsigned int pk = bents[ebase + e];
        int i = (int)(pk >> 16) - base;
        int r = atomicAdd(&lcur[i], 1);
        outl[r] = (unsigned short)(pk & 0xFFFFu);
    }
    __syncthreads();
    int total = ecnt + nn;
    for (int i = tid; i < total; i += 512)
        csr16[st + i] = outl[i];
    for (int idx = tid; idx < nn * 16; idx += 512) {
        int i = idx >> 4, j = idx & 15;
        float di = 1.0f / sqrtf((float)(counts[i] + 1));
        if (j == 0) dinv[base + i] = di;
        float xv2 = (j < F_IN) ? x[(long)(base + i) * F_IN + j] * di : 0.f;
        x16h[(long)(base + i) * 16 + j] = __float2half(xv2);
    }
}

// ---------------- layer 1 fused: agg(x16h) + GEMM W1 + relu -> h1 fp16 ----------------

__global__ void agg16_gemm_kernel(const __half* __restrict__ x16h, const int2* __restrict__ begend,
                                  const unsigned short* __restrict__ csr16,
                                  const float* __restrict__ dinv, const float* __restrict__ W1,
                                  const float* __restrict__ b1, __half* __restrict__ h1h, int n) {
    __shared__ float2 W1s[F_IN][64];
    __shared__ float2 bs[64];
    int tid = threadIdx.x;
    for (int i = tid; i < F_IN * 64; i += 256) {
        int k = i >> 6, j = i & 63;
        W1s[k][j] = make_float2(W1[k * HIDDEN + 2 * j], W1[k * HIDDEN + 2 * j + 1]);
    }
    if (tid < 64) bs[tid] = make_float2(b1[2 * tid], b1[2 * tid + 1]);
    __syncthreads();
    int node = (int)(((long)blockIdx.x * blockDim.x + threadIdx.x) >> 6);
    int lane = threadIdx.x & 63;
    if (node >= n) return;
    int grp = lane >> 4, f = lane & 15;
    int2 be = begend[node];
    int beg = be.x, end = be.y;
    float acc = 0.f;
    int eb = beg;
    for (; eb + 16 <= end; eb += 16) {
        int s[4]; __half v[4];
#pragma unroll
        for (int j = 0; j < 4; ++j) s[j] = csr16[eb + grp + 4 * j];
#pragma unroll
        for (int j = 0; j < 4; ++j) v[j] = x16h[(long)s[j] * 16 + f];
#pragma unroll
        for (int j = 0; j < 4; ++j) acc += __half2float(v[j]);
    }
    if (eb + 8 <= end) {
        int s0 = csr16[eb + grp], s1 = csr16[eb + grp + 4];
        acc += __half2float(x16h[(long)s0 * 16 + f]) + __half2float(x16h[(long)s1 * 16 + f]);
        eb += 8;
    }
    for (int e = eb + grp; e < end; e += 4)
        acc += __half2float(x16h[(long)csr16[e] * 16 + f]);
    acc += __shfl_down(acc, 32);
    acc += __shfl_down(acc, 16);
    float z = acc * dinv[node];          // valid in lanes 0..15
    float2 o = bs[lane];
#pragma unroll
    for (int k = 0; k < F_IN; ++k) {
        float zk = __shfl(z, k);
        float2 w = W1s[k][lane];
        o.x += zk * w.x;
        o.y += zk * w.y;
    }
    __half2 h = __floats2half2_rn(fmaxf(o.x, 0.f), fmaxf(o.y, 0.f));
    ((__half2*)h1h)[(long)node * 64 + lane] = h;
}

// ---------------- layer-2 GEMM: MFMA f16, W2Th pre-converted ----------------

__global__ __launch_bounds__(256) void gemm_mfma_kernel(
        const __half* __restrict__ h1h, const __half* __restrict__ W2Th,
        const float* __restrict__ dinv, __half* __restrict__ hsh, int n) {
    __shared__ _Float16 W2T[128 * 136];    // [n][k], stride 136
    __shared__ _Float16 outs[64 * 136];    // [node][feat], stride 136
    int tid = threadIdx.x;
    for (int i = tid; i < 128 * 16; i += 256) {
        int r = i >> 4, q = i & 15;
        *(uint4*)&W2T[r * 136 + q * 8] = ((const uint4*)W2Th)[r * 16 + q];
    }
    int base = blockIdx.x * 64;
    int lane = tid & 63, wid = tid >> 6;
    int l15 = lane & 15, quad = lane >> 4;
    int arow = base + wid * 16 + l15;
    if (arow >= n) arow = n - 1;           // clamp: safe reads, invalid rows unwritten
    const _Float16* Aptr = (const _Float16*)h1h + (size_t)arow * 128;
    floatx4 acc[8];
#pragma unroll
    for (int t = 0; t < 8; ++t) acc[t] = (floatx4){0.f, 0.f, 0.f, 0.f};
    __syncthreads();
#pragma unroll
    for (int c = 0; c < 4; ++c) {
        half8 a = *(const half8*)(Aptr + c * 32 + quad * 8);
#pragma unroll
        for (int t = 0; t < 8; ++t) {
            half8 b = *(const half8*)(&W2T[(t * 16 + l15) * 136 + c * 32 + quad * 8]);
            acc[t] = __builtin_amdgcn_mfma_f32_16x16x32_f16(a, b, acc[t], 0, 0, 0);
        }
    }
    float dv[4];
#pragma unroll
    for (int r = 0; r < 4; ++r) {
        int nd = base + wid * 16 + quad * 4 + r;
        dv[r] = dinv[(nd < n) ? nd : 0];
    }
#pragma unroll
    for (int t = 0; t < 8; ++t)
#pragma unroll
        for (int r = 0; r < 4; ++r)
            outs[(wid * 16 + quad * 4 + r) * 136 + t * 16 + l15] = (_Float16)(acc[t][r] * dv[r]);
    __syncthreads();
    for (int i = tid; i < 64 * 16; i += 256) {
        int ln = i >> 4, qq = i & 15;
        long nd = base + ln;
        if (nd < n) {
            uint4 u = *(uint4*)&outs[ln * 136 + qq * 8];
            ((uint4*)hsh)[nd * 16 + qq] = u;
        }
    }
}

// ---------------- layer-2 agg + fused y (fast epilogue) ----------------
// wave per node. Gather/reduce h2, relu+bias, stage h2 in LDS, then
// 128->19 GEMV vs TRANSPOSED W3l: lane j (j=lane&31<19), k-half = lane>>5,
// 16 float4 iterations. No early returns (block barriers).

__global__ void agg128y_kernel(const __half* __restrict__ hsh, const int2* __restrict__ begend,
                               const unsigned short* __restrict__ csr16, const float* __restrict__ dinv,
                               const float* __restrict__ bias, const float* __restrict__ W3l,
                               __half* __restrict__ y32h, int n) {
    __shared__ float W3lT[NCLS * 132];     // [j][k], stride 132 (float4-aligned); 10KB
    __shared__ float h2s[4][HIDDEN];       // 2KB
    int tid = threadIdx.x;
    for (int i = tid; i < NCLS * HIDDEN; i += 256) {
        int j = i >> 7, k = i & 127;
        W3lT[j * 132 + k] = W3l[k * NCLS + j];
    }
    __syncthreads();
    int wid = tid >> 6, lane = tid & 63;
    int node = blockIdx.x * 4 + wid;
    bool valid = node < n;
    int nd = valid ? node : 0;
    int grp = lane >> 5, q = lane & 31;
    int2 be = valid ? begend[nd] : make_int2(0, 0);
    int beg = be.x, end = be.y;
    float4 acc = make_float4(0.f, 0.f, 0.f, 0.f);
    int eb = beg;
    for (; eb + 16 <= end; eb += 16) {
        int s[8]; uint2 u[8];
#pragma unroll
        for (int j = 0; j < 8; ++j) s[j] = csr16[eb + grp + 2 * j];
#pragma unroll
        for (int j = 0; j < 8; ++j) u[j] = ((const uint2*)hsh)[(long)s[j] * 32 + q];
#pragma unroll
        for (int j = 0; j < 8; ++j) {
            float2 lo = __half22float2(*(__half2*)&u[j].x);
            float2 hi = __half22float2(*(__half2*)&u[j].y);
            acc.x += lo.x; acc.y += lo.y; acc.z += hi.x; acc.w += hi.y;
        }
    }
    if (eb + 8 <= end) {
        int s[4]; uint2 u[4];
#pragma unroll
        for (int j = 0; j < 4; ++j) s[j] = csr16[eb + grp + 2 * j];
#pragma unroll
        for (int j = 0; j < 4; ++j) u[j] = ((const uint2*)hsh)[(long)s[j] * 32 + q];
#pragma unroll
        for (int j = 0; j < 4; ++j) {
            float2 lo = __half22float2(*(__half2*)&u[j].x);
            float2 hi = __half22float2(*(__half2*)&u[j].y);
            acc.x += lo.x; acc.y += lo.y; acc.z += hi.x; acc.w += hi.y;
        }
        eb += 8;
    }
    for (int e = eb + grp; e < end; e += 2) {
        uint2 u = ((const uint2*)hsh)[(long)csr16[e] * 32 + q];
        float2 lo = __half22float2(*(__half2*)&u.x);
        float2 hi = __half22float2(*(__half2*)&u.y);
        acc.x += lo.x; acc.y += lo.y; acc.z += hi.x; acc.w += hi.y;
    }
    acc.x += __shfl_down(acc.x, 32);
    acc.y += __shfl_down(acc.y, 32);
    acc.z += __shfl_down(acc.z, 32);
    acc.w += __shfl_down(acc.w, 32);
    float di = dinv[nd];
    if (grp == 0) {
        float4 b = ((const float4*)bias)[q];
        float4 h2;
        h2.x = fmaxf(acc.x * di + b.x, 0.f);
        h2.y = fmaxf(acc.y * di + b.y, 0.f);
        h2.z = fmaxf(acc.z * di + b.z, 0.f);
        h2.w = fmaxf(acc.w * di + b.w, 0.f);
        *(float4*)&h2s[wid][4 * q] = h2;
    }
    __syncthreads();
    // GEMV: col j = lane&31 (j<19 active), k-half = grp; 16 float4 iters
    int j = lane & 31;
    float y = 0.f;
    if (j < NCLS) {
        const float* hv = h2s[wid] + grp * 64;
        const float* wv = W3lT + j * 132 + grp * 64;
#pragma unroll
        for (int it = 0; it < 16; ++it) {
            float4 h4 = *(const float4*)(hv + 4 * it);
            float4 w4 = *(const float4*)(wv + 4 * it);
            y += h4.x * w4.x + h4.y * w4.y + h4.z * w4.z + h4.w * w4.w;
        }
    }
    y += __shfl_down(y, 32);
    if (valid && lane < 32) {
        __half o = (lane < NCLS) ? __float2half(y * di) : __half(0.f);
        y32h[(long)node * 32 + lane] = o;
    }
}

// ---------------- pool + head ----------------

__global__ void agg24h_pool_kernel(const __half* __restrict__ ys, const int2* __restrict__ begend,
                                   const unsigned short* __restrict__ csr16, const float* __restrict__ dinv,
                                   const int* __restrict__ batch, float* __restrict__ pool, int n) {
    int node = (int)(((long)blockIdx.x * blockDim.x + threadIdx.x) >> 6);
    int lane = threadIdx.x & 63;
    if (node >= n) return;
    int grp = lane >> 4, f = lane & 15;
    int2 be = begend[node];
    int beg = be.x, end = be.y;
    float2 acc = {0.f, 0.f};
    int eb = beg;
    for (; eb + 32 <= end; eb += 32) {
        int s[8]; unsigned int u[8];
#pragma unroll
        for (int j = 0; j < 8; ++j) s[j] = csr16[eb + grp + 4 * j];
#pragma unroll
        for (int j = 0; j < 8; ++j) u[j] = ((const unsigned int*)ys)[(long)s[j] * 16 + f];
#pragma unroll
        for (int j = 0; j < 8; ++j) {
            float2 v = __half22float2(*(__half2*)&u[j]);
            acc.x += v.x; acc.y += v.y;
        }
    }
    if (eb + 16 <= end) {
        int s[4]; unsigned int u[4];
#pragma unroll
        for (int j = 0; j < 4; ++j) s[j] = csr16[eb + grp + 4 * j];
#pragma unroll
        for (int j = 0; j < 4; ++j) u[j] = ((const unsigned int*)ys)[(long)s[j] * 16 + f];
#pragma unroll
        for (int j = 0; j < 4; ++j) {
            float2 v = __half22float2(*(__half2*)&u[j]);
            acc.x += v.x; acc.y += v.y;
        }
        eb += 16;
    }
    for (int e = eb + grp; e < end; e += 4) {
        unsigned int u = ((const unsigned int*)ys)[(long)csr16[e] * 16 + f];
        float2 v = __half22float2(*(__half2*)&u);
        acc.x += v.x; acc.y += v.y;
    }
    acc.x += __shfl_down(acc.x, 32);
    acc.y += __shfl_down(acc.y, 32);
    acc.x += __shfl_down(acc.x, 16);
    acc.y += __shfl_down(acc.y, 16);
    if (lane < 16) {
        int g = batch[node];
        float sc = dinv[node];
        int c0 = 2 * f;
        if (c0 < NCLS) atomicAdd(&pool[(long)g * 24 + c0], acc.x * sc);
        if (c0 + 1 < NCLS) atomicAdd(&pool[(long)g * 24 + c0 + 1], acc.y * sc);
    }
}

__global__ void final_kernel(const float* __restrict__ pool, const float* __restrict__ cnt,
                             const float* __restrict__ b3l, const float* __restrict__ bl,
                             float* __restrict__ out, int G) {
    int i = blockIdx.x * blockDim.x + threadIdx.x;
    if (i >= G * NCLS) return;
    int g = i / NCLS, j = i % NCLS;
    float c = cnt[g];
    out[i] = (c > 0.f) ? pool[(long)g * 24 + j] / c + b3l[j] + bl[j] : bl[j];
}

// ---------------- launch ----------------

static inline size_t align256(size_t x) { return (x + 255) & ~(size_t)255; }

extern "C" void kernel_launch(void* const* d_in, const int* in_sizes, int n_in,
                              void* d_out, int out_size, void* d_ws, size_t ws_size,
                              hipStream_t stream) {
    const float* x    = (const float*)d_in[0];
    const int*   ei   = (const int*)d_in[1];
    const int*   batch= (const int*)d_in[2];
    const float* W1   = (const float*)d_in[3];
    const float* b1   = (const float*)d_in[4];
    const float* W2   = (const float*)d_in[5];
    const float* b2   = (const float*)d_in[6];
    const float* W3   = (const float*)d_in[7];
    const float* b3   = (const float*)d_in[8];
    const float* Wl   = (const float*)d_in[9];
    const float* bl   = (const float*)d_in[10];
    float* out = (float*)d_out;

    const int N = in_sizes[0] / F_IN;
    const int E = in_sizes[1] / 2;
    const int G = out_size / NCLS;
    const int* src = ei;
    const int* dst = ei + E;
    const int nSB = (E + EPB - 1) / EPB;
    const int nBK = (N + RNODES - 1) / RNODES;
    // cap: mean edges per USED bucket = E*RNODES/N; +768 (~12 sigma) slack
    int cap = (int)((long long)E * RNODES / N) + 768;
    if (cap + RNODES > OUTL_CAP) cap = OUTL_CAP - RNODES;
    const int rst = cap + RNODES;

    // workspace carve-up
    char* p = (char*)d_ws;
    size_t off = 0;
    unsigned int*   bents  = (unsigned int*)(p + off);   off = align256(off + (size_t)NB * cap * 4);
    unsigned short* csr16  = (unsigned short*)(p + off); off = align256(off + (size_t)NB * rst * 2);
    int2*           begend = (int2*)(p + off);           off = align256(off + (size_t)N * 8);
    float*          dinv   = (float*)(p + off);          off = align256(off + (size_t)N * 4);
    __half*         x16h   = (__half*)(p + off);         off = align256(off + (size_t)N * 16 * 2);
    __half*         h1h    = (__half*)(p + off);         off = align256(off + (size_t)N * HIDDEN * 2);
    __half*         hsh    = (__half*)(p + off);         off = align256(off + (size_t)N * HIDDEN * 2);
    __half*         y32h   = (__half*)(p + off);         off = align256(off + (size_t)N * 32 * 2);
    __half*         W2Th   = (__half*)(p + off);         off = align256(off + (size_t)HIDDEN * HIDDEN * 2);
    float*          W3l    = (float*)(p + off);          off = align256(off + (size_t)HIDDEN * NCLS * 4);
    float*          b3l    = (float*)(p + off);          off = align256(off + (size_t)NCLS * 4);
    float*          pool   = (float*)(p + off);
    float*          gcnt   = pool + (size_t)G * 24;
    int*            bcur   = (int*)(pool + (size_t)G * 25);  // adjacent: one memset covers all
    off = align256(off + (size_t)G * 25 * 4 + NB * 4);
    (void)ws_size; (void)n_in;

    // one memset zeroes pool, gcnt, and bcur
    hipMemsetAsync(pool, 0, (size_t)G * 25 * 4 + NB * 4, stream);

    // CSR build (scatter includes w3l + W2 fp16 conversion as extra blocks)
    scatter_kernel<<<nSB + 15, 256, 0, stream>>>(src, dst, bcur, bents, E, cap, nSB,
                                                 W3, Wl, b3, W3l, b3l, W2, W2Th);
    build_kernel<<<nBK, 512, 0, stream>>>(bents, bcur, x, batch, begend, csr16,
                                          dinv, gcnt, x16h, N, cap, rst);

    const int aggBlocks = (N + 3) / 4;  // 4 waves/block, wave per node

    // layer 1 fused: h1 = relu((dinv*sum x16h)@W1 + b1) -> fp16
    agg16_gemm_kernel<<<aggBlocks, 256, 0, stream>>>(x16h, begend, csr16, dinv, W1, b1, h1h, N);

    // layer 2: hsh = half((h1@W2)*dinv) row-major [MFMA]
    gemm_mfma_kernel<<<(N + 63) / 64, 256, 0, stream>>>(h1h, W2Th, dinv, hsh, N);

    // layer-2 agg + fused layer-3 GEMV: y32h = ((relu(dinv*sum hsh + b2)) @ W3l) * dinv
    agg128y_kernel<<<aggBlocks, 256, 0, stream>>>(hsh, begend, csr16, dinv, b2, W3l, y32h, N);

    // pool + head
    agg24h_pool_kernel<<<aggBlocks, 256, 0, stream>>>(y32h, begend, csr16, dinv, batch, pool, N);
    final_kernel<<<(G * NCLS + 255) / 256, 256, 0, stream>>>(pool, gcnt, b3l, bl, out, G);
}

// Round 16
// 234.952 us; speedup vs baseline: 1.0048x; 1.0048x over previous
//
#include <hip/hip_runtime.h>
#include <hip/hip_bf16.h>
#include <hip/hip_fp16.h>

// GCN2: 3x GCNConv(relu,relu,none) + global_mean_pool + linear head.
// R16 = R13 (best measured, 231.6us) with agg128h widened: 4 edge-groups x
// 16 lanes x uint4 (was 2 x 32 x uint2) -> 2x rows in flight per wave at
// same instruction count. R14/R15's y-fusion reverted (epilogue cost >=
// launch+roundtrip savings; R15's transposed staging was uncoalesced).

#define HIDDEN 128
#define F_IN 11
#define NCLS 19
#define NBITS 8
#define NB 256
#define RNODES 256
#define EPB 4096
#define OUTL_CAP 5376

typedef _Float16 half8 __attribute__((ext_vector_type(8)));
typedef float floatx4 __attribute__((ext_vector_type(4)));

// ---------------- scatter (+ folded w3l / W2 conversion blocks) ----------------

__global__ void scatter_kernel(const int* __restrict__ src, const int* __restrict__ dst,
                               int* __restrict__ bcur, unsigned int* __restrict__ bents,
                               int E, int cap, int nSB,
                               const float* __restrict__ W3, const float* __restrict__ Wl,
                               const float* __restrict__ b3, float* __restrict__ W3l,
                               float* __restrict__ b3l, const float* __restrict__ W2,
                               __half* __restrict__ W2Th) {
    __shared__ int hist[NB];
    __shared__ int binoff[NB];
    __shared__ int runrel[NB];
    __shared__ unsigned int ebuf[EPB];
    __shared__ unsigned short binOf[EPB];
    __shared__ int cw[4];
    int tid = threadIdx.x, lane = tid & 63, w = tid >> 6;

    if (blockIdx.x >= nSB) {                 // ---- folded precompute blocks ----
        int xb = blockIdx.x - nSB;
        if (xb < 11) {
            float* Wls = (float*)ebuf;       // alias: 128*19 floats = 9.7KB
            for (int i = tid; i < HIDDEN * NCLS; i += 256) Wls[i] = Wl[i];
            __syncthreads();
            if (xb < 10) {
                int o = xb * 256 + tid;
                if (o < HIDDEN * NCLS) {
                    int i = o / NCLS, j = o % NCLS;
                    float acc = 0.f;
#pragma unroll 8
                    for (int k = 0; k < HIDDEN; ++k) acc += W3[i * HIDDEN + k] * Wls[k * NCLS + j];
                    W3l[o] = acc;
                }
            } else if (tid < NCLS) {
                float acc = 0.f;
#pragma unroll 8
                for (int k = 0; k < HIDDEN; ++k) acc += b3[k] * Wls[k * NCLS + tid];
                b3l[tid] = acc;
            }
        } else {                              // xb 11..14: W2Th[n][k] = fp16(W2[k][n])
            int base = (xb - 11) * 4096;
#pragma unroll
            for (int r = 0; r < 16; ++r) {
                int idx = base + tid + 256 * r;
                int k = idx >> 7, nn2 = idx & 127;
                W2Th[nn2 * HIDDEN + k] = __float2half(W2[idx]);
            }
        }
        return;
    }

    // ---- scatter proper ----
    int base = blockIdx.x * EPB;
    int cnt = min(EPB, E - base);
    for (int i = tid; i < NB; i += 256) hist[i] = 0;
    __syncthreads();
    unsigned int pk[16];
    int rk[16];
#pragma unroll
    for (int j = 0; j < 16; ++j) {
        int idx = tid + 256 * j;
        if (idx < cnt) {
            int e = base + idx;
            int s = src[e], d = dst[e];
            pk[j] = (unsigned int)s | ((unsigned int)d << 16);
            int bin = d >> NBITS;
            int r = atomicAdd(&hist[bin], 1);
            rk[j] = r | (bin << 16);
        } else rk[j] = -1;
    }
    __syncthreads();
    int v = hist[tid], xv = v;                 // 256 threads scan 256 bins
#pragma unroll
    for (int d = 1; d < 64; d <<= 1) {
        int t = __shfl_up(xv, d, 64);
        if (lane >= d) xv += t;
    }
    if (lane == 63) cw[w] = xv;
    __syncthreads();
    int waveoff = 0;
    for (int wi = 0; wi < w; ++wi) waveoff += cw[wi];
    binoff[tid] = waveoff + xv - v;
    runrel[tid] = v ? atomicAdd(&bcur[tid], v) : 0;
    __syncthreads();
#pragma unroll
    for (int j = 0; j < 16; ++j) {
        if (rk[j] >= 0) {
            int bin = rk[j] >> 16, r = rk[j] & 0xFFFF;
            int pos = binoff[bin] + r;
            ebuf[pos] = pk[j];
            binOf[pos] = (unsigned short)bin;
        }
    }
    __syncthreads();
    for (int i = tid; i < cnt; i += 256) {
        int bin = binOf[i];
        int rel = runrel[bin] + (i - binoff[bin]);
        if (rel < cap)                          // hard guard: never cross regions
            bents[bin * cap + rel] = ebuf[i];
    }
}

// per bucket (256 nodes): counts -> scan -> LDS scatter -> dense writes. 512 threads.
__global__ void build_kernel(const unsigned int* __restrict__ bents, const int* __restrict__ bcur,
                             const float* __restrict__ x, const int* __restrict__ batch,
                             int2* __restrict__ begend, unsigned short* __restrict__ csr16,
                             float* __restrict__ dinv, float* __restrict__ gcnt,
                             __half* __restrict__ x16h, int n, int cap, int rst) {
    __shared__ int counts[RNODES];
    __shared__ int lcur[RNODES];
    __shared__ unsigned short outl[OUTL_CAP];
    __shared__ int wsums[4];
    int tid = threadIdx.x;          // 512
    int lane = tid & 63, w = tid >> 6;
    int b = blockIdx.x;
    int base = b << NBITS;
    int nn = min(RNODES, n - base);
    int ebase = b * cap;
    int ecnt = min(bcur[b], cap);   // hard guard
    int st = b * rst;
    for (int i = tid; i < RNODES; i += 512) counts[i] = 0;
    __syncthreads();
    for (int e = tid; e < ecnt; e += 512)
        atomicAdd(&counts[(bents[ebase + e] >> 16) - base], 1);
    __syncthreads();
    int v = 0, xv = 0;
    if (tid < RNODES) {             // 4 waves scan 256 entries
        v = (tid < nn) ? counts[tid] + 1 : 0;
        xv = v;
#pragma unroll
        for (int d = 1; d < 64; d <<= 1) {
            int t = __shfl_up(xv, d, 64);
            if (lane >= d) xv += t;
        }
        if (lane == 63) wsums[w] = xv;
    }
    __syncthreads();
    if (tid < nn) {
        int waveoff = 0;
        for (int wi = 0; wi < w; ++wi) waveoff += wsums[wi];
        int excl = waveoff + xv - v;
        lcur[tid] = excl + 1;
        outl[excl] = (unsigned short)(base + tid);        // self-loop slot 0
        begend[base + tid] = make_int2(st + excl, st + excl + v);
        atomicAdd(&gcnt[batch[base + tid]], 1.0f);
    }
    __syncthreads();
    for (int e = tid; e < ecnt; e += 512) {
        unsigned int pk = bents[ebase + e];
        int i = (int)(pk >> 16) - base;
        int r = atomicAdd(&lcur[i], 1);
        outl[r] = (unsigned short)(pk & 0xFFFFu);
    }
    __syncthreads();
    int total = ecnt + nn;
    for (int i = tid; i < total; i += 512)
        csr16[st + i] = outl[i];
    for (int idx = tid; idx < nn * 16; idx += 512) {
        int i = idx >> 4, j = idx & 15;
        float di = 1.0f / sqrtf((float)(counts[i] + 1));
        if (j == 0) dinv[base + i] = di;
        float xv2 = (j < F_IN) ? x[(long)(base + i) * F_IN + j] * di : 0.f;
        x16h[(long)(base + i) * 16 + j] = __float2half(xv2);
    }
}

// ---------------- layer 1 fused: agg(x16h) + GEMM W1 + relu -> h1 fp16 ----------------

__global__ void agg16_gemm_kernel(const __half* __restrict__ x16h, const int2* __restrict__ begend,
                                  const unsigned short* __restrict__ csr16,
                                  const float* __restrict__ dinv, const float* __restrict__ W1,
                                  const float* __restrict__ b1, __half* __restrict__ h1h, int n) {
    __shared__ float2 W1s[F_IN][64];
    __shared__ float2 bs[64];
    int tid = threadIdx.x;
    for (int i = tid; i < F_IN * 64; i += 256) {
        int k = i >> 6, j = i & 63;
        W1s[k][j] = make_float2(W1[k * HIDDEN + 2 * j], W1[k * HIDDEN + 2 * j + 1]);
    }
    if (tid < 64) bs[tid] = make_float2(b1[2 * tid], b1[2 * tid + 1]);
    __syncthreads();
    int node = (int)(((long)blockIdx.x * blockDim.x + threadIdx.x) >> 6);
    int lane = threadIdx.x & 63;
    if (node >= n) return;
    int grp = lane >> 4, f = lane & 15;
    int2 be = begend[node];
    int beg = be.x, end = be.y;
    float acc = 0.f;
    int eb = beg;
    for (; eb + 16 <= end; eb += 16) {
        int s[4]; __half v[4];
#pragma unroll
        for (int j = 0; j < 4; ++j) s[j] = csr16[eb + grp + 4 * j];
#pragma unroll
        for (int j = 0; j < 4; ++j) v[j] = x16h[(long)s[j] * 16 + f];
#pragma unroll
        for (int j = 0; j < 4; ++j) acc += __half2float(v[j]);
    }
    if (eb + 8 <= end) {
        int s0 = csr16[eb + grp], s1 = csr16[eb + grp + 4];
        acc += __half2float(x16h[(long)s0 * 16 + f]) + __half2float(x16h[(long)s1 * 16 + f]);
        eb += 8;
    }
    for (int e = eb + grp; e < end; e += 4)
        acc += __half2float(x16h[(long)csr16[e] * 16 + f]);
    acc += __shfl_down(acc, 32);
    acc += __shfl_down(acc, 16);
    float z = acc * dinv[node];          // valid in lanes 0..15
    float2 o = bs[lane];
#pragma unroll
    for (int k = 0; k < F_IN; ++k) {
        float zk = __shfl(z, k);
        float2 w = W1s[k][lane];
        o.x += zk * w.x;
        o.y += zk * w.y;
    }
    __half2 h = __floats2half2_rn(fmaxf(o.x, 0.f), fmaxf(o.y, 0.f));
    ((__half2*)h1h)[(long)node * 64 + lane] = h;
}

// ---------------- layer-2 GEMM: MFMA f16, W2Th pre-converted ----------------

__global__ __launch_bounds__(256) void gemm_mfma_kernel(
        const __half* __restrict__ h1h, const __half* __restrict__ W2Th,
        const float* __restrict__ dinv, __half* __restrict__ hsh, int n) {
    __shared__ _Float16 W2T[128 * 136];    // [n][k], stride 136
    __shared__ _Float16 outs[64 * 136];    // [node][feat], stride 136
    int tid = threadIdx.x;
    for (int i = tid; i < 128 * 16; i += 256) {
        int r = i >> 4, q = i & 15;
        *(uint4*)&W2T[r * 136 + q * 8] = ((const uint4*)W2Th)[r * 16 + q];
    }
    int base = blockIdx.x * 64;
    int lane = tid & 63, wid = tid >> 6;
    int l15 = lane & 15, quad = lane >> 4;
    int arow = base + wid * 16 + l15;
    if (arow >= n) arow = n - 1;           // clamp: safe reads, invalid rows unwritten
    const _Float16* Aptr = (const _Float16*)h1h + (size_t)arow * 128;
    floatx4 acc[8];
#pragma unroll
    for (int t = 0; t < 8; ++t) acc[t] = (floatx4){0.f, 0.f, 0.f, 0.f};
    __syncthreads();
#pragma unroll
    for (int c = 0; c < 4; ++c) {
        half8 a = *(const half8*)(Aptr + c * 32 + quad * 8);
#pragma unroll
        for (int t = 0; t < 8; ++t) {
            half8 b = *(const half8*)(&W2T[(t * 16 + l15) * 136 + c * 32 + quad * 8]);
            acc[t] = __builtin_amdgcn_mfma_f32_16x16x32_f16(a, b, acc[t], 0, 0, 0);
        }
    }
    float dv[4];
#pragma unroll
    for (int r = 0; r < 4; ++r) {
        int nd = base + wid * 16 + quad * 4 + r;
        dv[r] = dinv[(nd < n) ? nd : 0];
    }
#pragma unroll
    for (int t = 0; t < 8; ++t)
#pragma unroll
        for (int r = 0; r < 4; ++r)
            outs[(wid * 16 + quad * 4 + r) * 136 + t * 16 + l15] = (_Float16)(acc[t][r] * dv[r]);
    __syncthreads();
    for (int i = tid; i < 64 * 16; i += 256) {
        int ln = i >> 4, qq = i & 15;
        long nd = base + ln;
        if (nd < n) {
            uint4 u = *(uint4*)&outs[ln * 136 + qq * 8];
            ((uint4*)hsh)[nd * 16 + qq] = u;
        }
    }
}

// ---------------- 128-wide agg (layer 2): 4 groups x 16 lanes x uint4 ----------------

__global__ void agg128h_kernel(const __half* __restrict__ hsh, const int2* __restrict__ begend,
                               const unsigned short* __restrict__ csr16, const float* __restrict__ dinv,
                               const float* __restrict__ bias, __half* __restrict__ outh, int n) {
    int node = (int)(((long)blockIdx.x * blockDim.x + threadIdx.x) >> 6);
    int lane = threadIdx.x & 63;
    if (node >= n) return;
    int grp = lane >> 4, q = lane & 15;    // 4 edge-groups, 16 lanes each; row = 16 uint4
    int2 be = begend[node];
    int beg = be.x, end = be.y;
    float acc[8];
#pragma unroll
    for (int i = 0; i < 8; ++i) acc[i] = 0.f;
    int eb = beg;
    for (; eb + 32 <= end; eb += 32) {     // 8-deep pipeline, 32 edges
        int s[8]; uint4 u[8];
#pragma unroll
        for (int j = 0; j < 8; ++j) s[j] = csr16[eb + grp + 4 * j];
#pragma unroll
        for (int j = 0; j < 8; ++j) u[j] = ((const uint4*)hsh)[(long)s[j] * 16 + q];
#pragma unroll
        for (int j = 0; j < 8; ++j) {
            float2 a = __half22float2(*(__half2*)&u[j].x);
            float2 b = __half22float2(*(__half2*)&u[j].y);
            float2 c = __half22float2(*(__half2*)&u[j].z);
            float2 d = __half22float2(*(__half2*)&u[j].w);
            acc[0] += a.x; acc[1] += a.y; acc[2] += b.x; acc[3] += b.y;
            acc[4] += c.x; acc[5] += c.y; acc[6] += d.x; acc[7] += d.y;
        }
    }
    if (eb + 16 <= end) {                  // 4-deep, 16 edges
        int s[4]; uint4 u[4];
#pragma unroll
        for (int j = 0; j < 4; ++j) s[j] = csr16[eb + grp + 4 * j];
#pragma unroll
        for (int j = 0; j < 4; ++j) u[j] = ((const uint4*)hsh)[(long)s[j] * 16 + q];
#pragma unroll
        for (int j = 0; j < 4; ++j) {
            float2 a = __half22float2(*(__half2*)&u[j].x);
            float2 b = __half22float2(*(__half2*)&u[j].y);
            float2 c = __half22float2(*(__half2*)&u[j].z);
            float2 d = __half22float2(*(__half2*)&u[j].w);
            acc[0] += a.x; acc[1] += a.y; acc[2] += b.x; acc[3] += b.y;
            acc[4] += c.x; acc[5] += c.y; acc[6] += d.x; acc[7] += d.y;
        }
        eb += 16;
    }
    for (int e = eb + grp; e < end; e += 4) {
        uint4 u = ((const uint4*)hsh)[(long)csr16[e] * 16 + q];
        float2 a = __half22float2(*(__half2*)&u.x);
        float2 b = __half22float2(*(__half2*)&u.y);
        float2 c = __half22float2(*(__half2*)&u.z);
        float2 d = __half22float2(*(__half2*)&u.w);
        acc[0] += a.x; acc[1] += a.y; acc[2] += b.x; acc[3] += b.y;
        acc[4] += c.x; acc[5] += c.y; acc[6] += d.x; acc[7] += d.y;
    }
#pragma unroll
    for (int i = 0; i < 8; ++i) {
        acc[i] += __shfl_down(acc[i], 32);
        acc[i] += __shfl_down(acc[i], 16);
    }
    if (grp == 0) {                        // lanes 0..15 hold full sums of 8 feats
        float di = dinv[node];
        float4 b0 = ((const float4*)bias)[2 * q];
        float4 b1v = ((const float4*)bias)[2 * q + 1];
        __half2 h0 = __floats2half2_rn(fmaxf(acc[0] * di + b0.x, 0.f), fmaxf(acc[1] * di + b0.y, 0.f));
        __half2 h1 = __floats2half2_rn(fmaxf(acc[2] * di + b0.z, 0.f), fmaxf(acc[3] * di + b0.w, 0.f));
        __half2 h2 = __floats2half2_rn(fmaxf(acc[4] * di + b1v.x, 0.f), fmaxf(acc[5] * di + b1v.y, 0.f));
        __half2 h3 = __floats2half2_rn(fmaxf(acc[6] * di + b1v.z, 0.f), fmaxf(acc[7] * di + b1v.w, 0.f));
        uint4 u;
        u.x = *(unsigned int*)&h0; u.y = *(unsigned int*)&h1;
        u.z = *(unsigned int*)&h2; u.w = *(unsigned int*)&h3;
        ((uint4*)outh)[(long)node * 16 + q] = u;
    }
}

// ---------------- folded layer 3 + pool + head ----------------

// y32h[n,32] = (h2h @ W3l)*dinv, cols 19..31 zero; 12 nodes/block; h2 fp16 in
__global__ void gemm_y32h_kernel(const __half* __restrict__ h2h, const float* __restrict__ W3l,
                                 const float* __restrict__ dinv, __half* __restrict__ ys, int n) {
    __shared__ float hs[12][HIDDEN];
    __shared__ float Ws[HIDDEN][20];
    int tid = threadIdx.x;
    long base = (long)blockIdx.x * 12;
    for (int i = tid; i < HIDDEN * NCLS; i += 256) Ws[i / NCLS][i % NCLS] = W3l[i];
    for (int idx = tid; idx < 12 * 32; idx += 256) {
        int node = idx >> 5, q = idx & 31;
        long gn = base + node;
        uint2 u = (gn < n) ? ((const uint2*)h2h)[gn * 32 + q] : make_uint2(0u, 0u);
        float2 lo = __half22float2(*(__half2*)&u.x);
        float2 hi = __half22float2(*(__half2*)&u.y);
        hs[node][q * 4] = lo.x; hs[node][q * 4 + 1] = lo.y;
        hs[node][q * 4 + 2] = hi.x; hs[node][q * 4 + 3] = hi.y;
    }
    __syncthreads();
    if (tid < 12 * NCLS) {
        int node = tid / NCLS, j = tid % NCLS;
        long gn = base + node;
        if (gn < n) {
            float acc = 0.f;
#pragma unroll 8
            for (int k = 0; k < HIDDEN; ++k) acc += hs[node][k] * Ws[k][j];
            ys[gn * 32 + j] = __float2half(acc * dinv[gn]);
        }
    }
    for (int idx = tid; idx < 12 * 13; idx += 256) {
        int node = idx / 13, j = 19 + idx % 13;
        long gn = base + node;
        if (gn < n) ys[gn * 32 + j] = __half(0.f);
    }
}

__global__ void agg24h_pool_kernel(const __half* __restrict__ ys, const int2* __restrict__ begend,
                                   const unsigned short* __restrict__ csr16, const float* __restrict__ dinv,
                                   const int* __restrict__ batch, float* __restrict__ pool, int n) {
    int node = (int)(((long)blockIdx.x * blockDim.x + threadIdx.x) >> 6);
    int lane = threadIdx.x & 63;
    if (node >= n) return;
    int grp = lane >> 4, f = lane & 15;
    int2 be = begend[node];
    int beg = be.x, end = be.y;
    float2 acc = {0.f, 0.f};
    int eb = beg;
    for (; eb + 32 <= end; eb += 32) {
        int s[8]; unsigned int u[8];
#pragma unroll
        for (int j = 0; j < 8; ++j) s[j] = csr16[eb + grp + 4 * j];
#pragma unroll
        for (int j = 0; j < 8; ++j) u[j] = ((const unsigned int*)ys)[(long)s[j] * 16 + f];
#pragma unroll
        for (int j = 0; j < 8; ++j) {
            float2 v = __half22float2(*(__half2*)&u[j]);
            acc.x += v.x; acc.y += v.y;
        }
    }
    if (eb + 16 <= end) {
        int s[4]; unsigned int u[4];
#pragma unroll
        for (int j = 0; j < 4; ++j) s[j] = csr16[eb + grp + 4 * j];
#pragma unroll
        for (int j = 0; j < 4; ++j) u[j] = ((const unsigned int*)ys)[(long)s[j] * 16 + f];
#pragma unroll
        for (int j = 0; j < 4; ++j) {
            float2 v = __half22float2(*(__half2*)&u[j]);
            acc.x += v.x; acc.y += v.y;
        }
        eb += 16;
    }
    for (int e = eb + grp; e < end; e += 4) {
        unsigned int u = ((const unsigned int*)ys)[(long)csr16[e] * 16 + f];
        float2 v = __half22float2(*(__half2*)&u);
        acc.x += v.x; acc.y += v.y;
    }
    acc.x += __shfl_down(acc.x, 32);
    acc.y += __shfl_down(acc.y, 32);
    acc.x += __shfl_down(acc.x, 16);
    acc.y += __shfl_down(acc.y, 16);
    if (lane < 16) {
        int g = batch[node];
        float sc = dinv[node];
        int c0 = 2 * f;
        if (c0 < NCLS) atomicAdd(&pool[(long)g * 24 + c0], acc.x * sc);
        if (c0 + 1 < NCLS) atomicAdd(&pool[(long)g * 24 + c0 + 1], acc.y * sc);
    }
}

__global__ void final_kernel(const float* __restrict__ pool, const float* __restrict__ cnt,
                             const float* __restrict__ b3l, const float* __restrict__ bl,
                             float* __restrict__ out, int G) {
    int i = blockIdx.x * blockDim.x + threadIdx.x;
    if (i >= G * NCLS) return;
    int g = i / NCLS, j = i % NCLS;
    float c = cnt[g];
    out[i] = (c > 0.f) ? pool[(long)g * 24 + j] / c + b3l[j] + bl[j] : bl[j];
}

// ---------------- launch ----------------

static inline size_t align256(size_t x) { return (x + 255) & ~(size_t)255; }

extern "C" void kernel_launch(void* const* d_in, const int* in_sizes, int n_in,
                              void* d_out, int out_size, void* d_ws, size_t ws_size,
                              hipStream_t stream) {
    const float* x    = (const float*)d_in[0];
    const int*   ei   = (const int*)d_in[1];
    const int*   batch= (const int*)d_in[2];
    const float* W1   = (const float*)d_in[3];
    const float* b1   = (const float*)d_in[4];
    const float* W2   = (const float*)d_in[5];
    const float* b2   = (const float*)d_in[6];
    const float* W3   = (const float*)d_in[7];
    const float* b3   = (const float*)d_in[8];
    const float* Wl   = (const float*)d_in[9];
    const float* bl   = (const float*)d_in[10];
    float* out = (float*)d_out;

    const int N = in_sizes[0] / F_IN;
    const int E = in_sizes[1] / 2;
    const int G = out_size / NCLS;
    const int* src = ei;
    const int* dst = ei + E;
    const int nSB = (E + EPB - 1) / EPB;
    const int nBK = (N + RNODES - 1) / RNODES;
    // cap: mean edges per USED bucket = E*RNODES/N; +768 (~12 sigma) slack
    int cap = (int)((long long)E * RNODES / N) + 768;
    if (cap + RNODES > OUTL_CAP) cap = OUTL_CAP - RNODES;
    const int rst = cap + RNODES;

    // workspace carve-up
    char* p = (char*)d_ws;
    size_t off = 0;
    unsigned int*   bents  = (unsigned int*)(p + off);   off = align256(off + (size_t)NB * cap * 4);
    unsigned short* csr16  = (unsigned short*)(p + off); off = align256(off + (size_t)NB * rst * 2);
    int2*           begend = (int2*)(p + off);           off = align256(off + (size_t)N * 8);
    float*          dinv   = (float*)(p + off);          off = align256(off + (size_t)N * 4);
    __half*         x16h   = (__half*)(p + off);         off = align256(off + (size_t)N * 16 * 2);
    __half*         h1h    = (__half*)(p + off);         off = align256(off + (size_t)N * HIDDEN * 2);
    __half*         hsh    = (__half*)(p + off);         off = align256(off + (size_t)N * HIDDEN * 2);
    __half*         h2h    = (__half*)(p + off);         off = align256(off + (size_t)N * HIDDEN * 2);
    __half*         y32h   = (__half*)(p + off);         off = align256(off + (size_t)N * 32 * 2);
    __half*         W2Th   = (__half*)(p + off);         off = align256(off + (size_t)HIDDEN * HIDDEN * 2);
    float*          W3l    = (float*)(p + off);          off = align256(off + (size_t)HIDDEN * NCLS * 4);
    float*          b3l    = (float*)(p + off);          off = align256(off + (size_t)NCLS * 4);
    float*          pool   = (float*)(p + off);
    float*          gcnt   = pool + (size_t)G * 24;
    int*            bcur   = (int*)(pool + (size_t)G * 25);  // adjacent: one memset covers all
    off = align256(off + (size_t)G * 25 * 4 + NB * 4);
    (void)ws_size; (void)n_in;

    // one memset zeroes pool, gcnt, and bcur
    hipMemsetAsync(pool, 0, (size_t)G * 25 * 4 + NB * 4, stream);

    // CSR build (scatter includes w3l + W2 fp16 conversion as extra blocks)
    scatter_kernel<<<nSB + 15, 256, 0, stream>>>(src, dst, bcur, bents, E, cap, nSB,
                                                 W3, Wl, b3, W3l, b3l, W2, W2Th);
    build_kernel<<<nBK, 512, 0, stream>>>(bents, bcur, x, batch, begend, csr16,
                                          dinv, gcnt, x16h, N, cap, rst);

    const int aggBlocks = (N + 3) / 4;  // 4 waves/block, wave per node

    // layer 1 fused: h1 = relu((dinv*sum x16h)@W1 + b1) -> fp16
    agg16_gemm_kernel<<<aggBlocks, 256, 0, stream>>>(x16h, begend, csr16, dinv, W1, b1, h1h, N);

    // layer 2: hsh = half((h1@W2)*dinv) row-major [MFMA] ; h2h = relu(dinv*sum + b2) fp16
    gemm_mfma_kernel<<<(N + 63) / 64, 256, 0, stream>>>(h1h, W2Th, dinv, hsh, N);
    agg128h_kernel<<<aggBlocks, 256, 0, stream>>>(hsh, begend, csr16, dinv, b2, h2h, N);

    // folded layer 3 + pool
    gemm_y32h_kernel<<<(N + 11) / 12, 256, 0, stream>>>(h2h, W3l, dinv, y32h, N);
    agg24h_pool_kernel<<<aggBlocks, 256, 0, stream>>>(y32h, begend, csr16, dinv, batch, pool, N);
    final_kernel<<<(G * NCLS + 255) / 256, 256, 0, stream>>>(pool, gcnt, b3l, bl, out, G);
}

// Round 17
// 230.336 us; speedup vs baseline: 1.0250x; 1.0200x over previous
//
#include <hip/hip_runtime.h>
#include <hip/hip_bf16.h>
#include <hip/hip_fp16.h>

// GCN2: 3x GCNConv(relu,relu,none) + global_mean_pool + linear head.
// FINAL (= R13, best measured at 231.6us): bucketed 2-kernel CSR build
// (capacity-padded, LDS-staged, hard-guarded), fused agg16+W1 layer 1,
// MFMA f16 layer-2 GEMM (W2 pre-converted in scatter's extra blocks),
// uint2 fp16 gathers with 8-deep register pipelines, folded W3@Wl head,
// atomic mean-pool. R14-R16 experiments (y-fusion, transposed-W3l epilogue,
// uint4 widening) were all neutral-to-negative -> reverted.

#define HIDDEN 128
#define F_IN 11
#define NCLS 19
#define NBITS 8
#define NB 256
#define RNODES 256
#define EPB 4096
#define OUTL_CAP 5376

typedef _Float16 half8 __attribute__((ext_vector_type(8)));
typedef float floatx4 __attribute__((ext_vector_type(4)));

// ---------------- scatter (+ folded w3l / W2 conversion blocks) ----------------

__global__ void scatter_kernel(const int* __restrict__ src, const int* __restrict__ dst,
                               int* __restrict__ bcur, unsigned int* __restrict__ bents,
                               int E, int cap, int nSB,
                               const float* __restrict__ W3, const float* __restrict__ Wl,
                               const float* __restrict__ b3, float* __restrict__ W3l,
                               float* __restrict__ b3l, const float* __restrict__ W2,
                               __half* __restrict__ W2Th) {
    __shared__ int hist[NB];
    __shared__ int binoff[NB];
    __shared__ int runrel[NB];
    __shared__ unsigned int ebuf[EPB];
    __shared__ unsigned short binOf[EPB];
    __shared__ int cw[4];
    int tid = threadIdx.x, lane = tid & 63, w = tid >> 6;

    if (blockIdx.x >= nSB) {                 // ---- folded precompute blocks ----
        int xb = blockIdx.x - nSB;
        if (xb < 11) {
            float* Wls = (float*)ebuf;       // alias: 128*19 floats = 9.7KB
            for (int i = tid; i < HIDDEN * NCLS; i += 256) Wls[i] = Wl[i];
            __syncthreads();
            if (xb < 10) {
                int o = xb * 256 + tid;
                if (o < HIDDEN * NCLS) {
                    int i = o / NCLS, j = o % NCLS;
                    float acc = 0.f;
#pragma unroll 8
                    for (int k = 0; k < HIDDEN; ++k) acc += W3[i * HIDDEN + k] * Wls[k * NCLS + j];
                    W3l[o] = acc;
                }
            } else if (tid < NCLS) {
                float acc = 0.f;
#pragma unroll 8
                for (int k = 0; k < HIDDEN; ++k) acc += b3[k] * Wls[k * NCLS + tid];
                b3l[tid] = acc;
            }
        } else {                              // xb 11..14: W2Th[n][k] = fp16(W2[k][n])
            int base = (xb - 11) * 4096;
#pragma unroll
            for (int r = 0; r < 16; ++r) {
                int idx = base + tid + 256 * r;
                int k = idx >> 7, nn2 = idx & 127;
                W2Th[nn2 * HIDDEN + k] = __float2half(W2[idx]);
            }
        }
        return;
    }

    // ---- scatter proper ----
    int base = blockIdx.x * EPB;
    int cnt = min(EPB, E - base);
    for (int i = tid; i < NB; i += 256) hist[i] = 0;
    __syncthreads();
    unsigned int pk[16];
    int rk[16];
#pragma unroll
    for (int j = 0; j < 16; ++j) {
        int idx = tid + 256 * j;
        if (idx < cnt) {
            int e = base + idx;
            int s = src[e], d = dst[e];
            pk[j] = (unsigned int)s | ((unsigned int)d << 16);
            int bin = d >> NBITS;
            int r = atomicAdd(&hist[bin], 1);
            rk[j] = r | (bin << 16);
        } else rk[j] = -1;
    }
    __syncthreads();
    int v = hist[tid], xv = v;                 // 256 threads scan 256 bins
#pragma unroll
    for (int d = 1; d < 64; d <<= 1) {
        int t = __shfl_up(xv, d, 64);
        if (lane >= d) xv += t;
    }
    if (lane == 63) cw[w] = xv;
    __syncthreads();
    int waveoff = 0;
    for (int wi = 0; wi < w; ++wi) waveoff += cw[wi];
    binoff[tid] = waveoff + xv - v;
    runrel[tid] = v ? atomicAdd(&bcur[tid], v) : 0;
    __syncthreads();
#pragma unroll
    for (int j = 0; j < 16; ++j) {
        if (rk[j] >= 0) {
            int bin = rk[j] >> 16, r = rk[j] & 0xFFFF;
            int pos = binoff[bin] + r;
            ebuf[pos] = pk[j];
            binOf[pos] = (unsigned short)bin;
        }
    }
    __syncthreads();
    for (int i = tid; i < cnt; i += 256) {
        int bin = binOf[i];
        int rel = runrel[bin] + (i - binoff[bin]);
        if (rel < cap)                          // hard guard: never cross regions
            bents[bin * cap + rel] = ebuf[i];
    }
}

// per bucket (256 nodes): counts -> scan -> LDS scatter -> dense writes. 512 threads.
__global__ void build_kernel(const unsigned int* __restrict__ bents, const int* __restrict__ bcur,
                             const float* __restrict__ x, const int* __restrict__ batch,
                             int2* __restrict__ begend, unsigned short* __restrict__ csr16,
                             float* __restrict__ dinv, float* __restrict__ gcnt,
                             __half* __restrict__ x16h, int n, int cap, int rst) {
    __shared__ int counts[RNODES];
    __shared__ int lcur[RNODES];
    __shared__ unsigned short outl[OUTL_CAP];
    __shared__ int wsums[4];
    int tid = threadIdx.x;          // 512
    int lane = tid & 63, w = tid >> 6;
    int b = blockIdx.x;
    int base = b << NBITS;
    int nn = min(RNODES, n - base);
    int ebase = b * cap;
    int ecnt = min(bcur[b], cap);   // hard guard
    int st = b * rst;
    for (int i = tid; i < RNODES; i += 512) counts[i] = 0;
    __syncthreads();
    for (int e = tid; e < ecnt; e += 512)
        atomicAdd(&counts[(bents[ebase + e] >> 16) - base], 1);
    __syncthreads();
    int v = 0, xv = 0;
    if (tid < RNODES) {             // 4 waves scan 256 entries
        v = (tid < nn) ? counts[tid] + 1 : 0;
        xv = v;
#pragma unroll
        for (int d = 1; d < 64; d <<= 1) {
            int t = __shfl_up(xv, d, 64);
            if (lane >= d) xv += t;
        }
        if (lane == 63) wsums[w] = xv;
    }
    __syncthreads();
    if (tid < nn) {
        int waveoff = 0;
        for (int wi = 0; wi < w; ++wi) waveoff += wsums[wi];
        int excl = waveoff + xv - v;
        lcur[tid] = excl + 1;
        outl[excl] = (unsigned short)(base + tid);        // self-loop slot 0
        begend[base + tid] = make_int2(st + excl, st + excl + v);
        atomicAdd(&gcnt[batch[base + tid]], 1.0f);
    }
    __syncthreads();
    for (int e = tid; e < ecnt; e += 512) {
        unsigned int pk = bents[ebase + e];
        int i = (int)(pk >> 16) - base;
        int r = atomicAdd(&lcur[i], 1);
        outl[r] = (unsigned short)(pk & 0xFFFFu);
    }
    __syncthreads();
    int total = ecnt + nn;
    for (int i = tid; i < total; i += 512)
        csr16[st + i] = outl[i];
    for (int idx = tid; idx < nn * 16; idx += 512) {
        int i = idx >> 4, j = idx & 15;
        float di = 1.0f / sqrtf((float)(counts[i] + 1));
        if (j == 0) dinv[base + i] = di;
        float xv2 = (j < F_IN) ? x[(long)(base + i) * F_IN + j] * di : 0.f;
        x16h[(long)(base + i) * 16 + j] = __float2half(xv2);
    }
}

// ---------------- layer 1 fused: agg(x16h) + GEMM W1 + relu -> h1 fp16 ----------------

__global__ void agg16_gemm_kernel(const __half* __restrict__ x16h, const int2* __restrict__ begend,
                                  const unsigned short* __restrict__ csr16,
                                  const float* __restrict__ dinv, const float* __restrict__ W1,
                                  const float* __restrict__ b1, __half* __restrict__ h1h, int n) {
    __shared__ float2 W1s[F_IN][64];
    __shared__ float2 bs[64];
    int tid = threadIdx.x;
    for (int i = tid; i < F_IN * 64; i += 256) {
        int k = i >> 6, j = i & 63;
        W1s[k][j] = make_float2(W1[k * HIDDEN + 2 * j], W1[k * HIDDEN + 2 * j + 1]);
    }
    if (tid < 64) bs[tid] = make_float2(b1[2 * tid], b1[2 * tid + 1]);
    __syncthreads();
    int node = (int)(((long)blockIdx.x * blockDim.x + threadIdx.x) >> 6);
    int lane = threadIdx.x & 63;
    if (node >= n) return;
    int grp = lane >> 4, f = lane & 15;
    int2 be = begend[node];
    int beg = be.x, end = be.y;
    float acc = 0.f;
    int eb = beg;
    for (; eb + 16 <= end; eb += 16) {
        int s[4]; __half v[4];
#pragma unroll
        for (int j = 0; j < 4; ++j) s[j] = csr16[eb + grp + 4 * j];
#pragma unroll
        for (int j = 0; j < 4; ++j) v[j] = x16h[(long)s[j] * 16 + f];
#pragma unroll
        for (int j = 0; j < 4; ++j) acc += __half2float(v[j]);
    }
    if (eb + 8 <= end) {
        int s0 = csr16[eb + grp], s1 = csr16[eb + grp + 4];
        acc += __half2float(x16h[(long)s0 * 16 + f]) + __half2float(x16h[(long)s1 * 16 + f]);
        eb += 8;
    }
    for (int e = eb + grp; e < end; e += 4)
        acc += __half2float(x16h[(long)csr16[e] * 16 + f]);
    acc += __shfl_down(acc, 32);
    acc += __shfl_down(acc, 16);
    float z = acc * dinv[node];          // valid in lanes 0..15
    float2 o = bs[lane];
#pragma unroll
    for (int k = 0; k < F_IN; ++k) {
        float zk = __shfl(z, k);
        float2 w = W1s[k][lane];
        o.x += zk * w.x;
        o.y += zk * w.y;
    }
    __half2 h = __floats2half2_rn(fmaxf(o.x, 0.f), fmaxf(o.y, 0.f));
    ((__half2*)h1h)[(long)node * 64 + lane] = h;
}

// ---------------- layer-2 GEMM: MFMA f16, W2Th pre-converted ----------------

__global__ __launch_bounds__(256) void gemm_mfma_kernel(
        const __half* __restrict__ h1h, const __half* __restrict__ W2Th,
        const float* __restrict__ dinv, __half* __restrict__ hsh, int n) {
    __shared__ _Float16 W2T[128 * 136];    // [n][k], stride 136
    __shared__ _Float16 outs[64 * 136];    // [node][feat], stride 136
    int tid = threadIdx.x;
    for (int i = tid; i < 128 * 16; i += 256) {
        int r = i >> 4, q = i & 15;
        *(uint4*)&W2T[r * 136 + q * 8] = ((const uint4*)W2Th)[r * 16 + q];
    }
    int base = blockIdx.x * 64;
    int lane = tid & 63, wid = tid >> 6;
    int l15 = lane & 15, quad = lane >> 4;
    int arow = base + wid * 16 + l15;
    if (arow >= n) arow = n - 1;           // clamp: safe reads, invalid rows unwritten
    const _Float16* Aptr = (const _Float16*)h1h + (size_t)arow * 128;
    floatx4 acc[8];
#pragma unroll
    for (int t = 0; t < 8; ++t) acc[t] = (floatx4){0.f, 0.f, 0.f, 0.f};
    __syncthreads();
#pragma unroll
    for (int c = 0; c < 4; ++c) {
        half8 a = *(const half8*)(Aptr + c * 32 + quad * 8);
#pragma unroll
        for (int t = 0; t < 8; ++t) {
            half8 b = *(const half8*)(&W2T[(t * 16 + l15) * 136 + c * 32 + quad * 8]);
            acc[t] = __builtin_amdgcn_mfma_f32_16x16x32_f16(a, b, acc[t], 0, 0, 0);
        }
    }
    float dv[4];
#pragma unroll
    for (int r = 0; r < 4; ++r) {
        int nd = base + wid * 16 + quad * 4 + r;
        dv[r] = dinv[(nd < n) ? nd : 0];
    }
#pragma unroll
    for (int t = 0; t < 8; ++t)
#pragma unroll
        for (int r = 0; r < 4; ++r)
            outs[(wid * 16 + quad * 4 + r) * 136 + t * 16 + l15] = (_Float16)(acc[t][r] * dv[r]);
    __syncthreads();
    for (int i = tid; i < 64 * 16; i += 256) {
        int ln = i >> 4, qq = i & 15;
        long nd = base + ln;
        if (nd < n) {
            uint4 u = *(uint4*)&outs[ln * 136 + qq * 8];
            ((uint4*)hsh)[nd * 16 + qq] = u;
        }
    }
}

// ---------------- 128-wide agg (layer 2): half in, half out (R13 proven) ----------------

__global__ void agg128h_kernel(const __half* __restrict__ hsh, const int2* __restrict__ begend,
                               const unsigned short* __restrict__ csr16, const float* __restrict__ dinv,
                               const float* __restrict__ bias, __half* __restrict__ outh, int n) {
    int node = (int)(((long)blockIdx.x * blockDim.x + threadIdx.x) >> 6);
    int lane = threadIdx.x & 63;
    if (node >= n) return;
    int grp = lane >> 5, q = lane & 31;
    int2 be = begend[node];
    int beg = be.x, end = be.y;
    float4 acc = make_float4(0.f, 0.f, 0.f, 0.f);
    int eb = beg;
    for (; eb + 16 <= end; eb += 16) {
        int s[8]; uint2 u[8];
#pragma unroll
        for (int j = 0; j < 8; ++j) s[j] = csr16[eb + grp + 2 * j];
#pragma unroll
        for (int j = 0; j < 8; ++j) u[j] = ((const uint2*)hsh)[(long)s[j] * 32 + q];
#pragma unroll
        for (int j = 0; j < 8; ++j) {
            float2 lo = __half22float2(*(__half2*)&u[j].x);
            float2 hi = __half22float2(*(__half2*)&u[j].y);
            acc.x += lo.x; acc.y += lo.y; acc.z += hi.x; acc.w += hi.y;
        }
    }
    if (eb + 8 <= end) {
        int s[4]; uint2 u[4];
#pragma unroll
        for (int j = 0; j < 4; ++j) s[j] = csr16[eb + grp + 2 * j];
#pragma unroll
        for (int j = 0; j < 4; ++j) u[j] = ((const uint2*)hsh)[(long)s[j] * 32 + q];
#pragma unroll
        for (int j = 0; j < 4; ++j) {
            float2 lo = __half22float2(*(__half2*)&u[j].x);
            float2 hi = __half22float2(*(__half2*)&u[j].y);
            acc.x += lo.x; acc.y += lo.y; acc.z += hi.x; acc.w += hi.y;
        }
        eb += 8;
    }
    for (int e = eb + grp; e < end; e += 2) {
        uint2 u = ((const uint2*)hsh)[(long)csr16[e] * 32 + q];
        float2 lo = __half22float2(*(__half2*)&u.x);
        float2 hi = __half22float2(*(__half2*)&u.y);
        acc.x += lo.x; acc.y += lo.y; acc.z += hi.x; acc.w += hi.y;
    }
    acc.x += __shfl_down(acc.x, 32);
    acc.y += __shfl_down(acc.y, 32);
    acc.z += __shfl_down(acc.z, 32);
    acc.w += __shfl_down(acc.w, 32);
    if (grp == 0) {
        float di = dinv[node];
        float4 b = ((const float4*)bias)[q];
        __half2 h01 = __floats2half2_rn(fmaxf(acc.x * di + b.x, 0.f), fmaxf(acc.y * di + b.y, 0.f));
        __half2 h23 = __floats2half2_rn(fmaxf(acc.z * di + b.z, 0.f), fmaxf(acc.w * di + b.w, 0.f));
        uint2 u = make_uint2(*(unsigned int*)&h01, *(unsigned int*)&h23);
        ((uint2*)outh)[(long)node * 32 + q] = u;
    }
}

// ---------------- folded layer 3 + pool + head ----------------

// y32h[n,32] = (h2h @ W3l)*dinv, cols 19..31 zero; 12 nodes/block; h2 fp16 in
__global__ void gemm_y32h_kernel(const __half* __restrict__ h2h, const float* __restrict__ W3l,
                                 const float* __restrict__ dinv, __half* __restrict__ ys, int n) {
    __shared__ float hs[12][HIDDEN];
    __shared__ float Ws[HIDDEN][20];
    int tid = threadIdx.x;
    long base = (long)blockIdx.x * 12;
    for (int i = tid; i < HIDDEN * NCLS; i += 256) Ws[i / NCLS][i % NCLS] = W3l[i];
    for (int idx = tid; idx < 12 * 32; idx += 256) {
        int node = idx >> 5, q = idx & 31;
        long gn = base + node;
        uint2 u = (gn < n) ? ((const uint2*)h2h)[gn * 32 + q] : make_uint2(0u, 0u);
        float2 lo = __half22float2(*(__half2*)&u.x);
        float2 hi = __half22float2(*(__half2*)&u.y);
        hs[node][q * 4] = lo.x; hs[node][q * 4 + 1] = lo.y;
        hs[node][q * 4 + 2] = hi.x; hs[node][q * 4 + 3] = hi.y;
    }
    __syncthreads();
    if (tid < 12 * NCLS) {
        int node = tid / NCLS, j = tid % NCLS;
        long gn = base + node;
        if (gn < n) {
            float acc = 0.f;
#pragma unroll 8
            for (int k = 0; k < HIDDEN; ++k) acc += hs[node][k] * Ws[k][j];
            ys[gn * 32 + j] = __float2half(acc * dinv[gn]);
        }
    }
    for (int idx = tid; idx < 12 * 13; idx += 256) {
        int node = idx / 13, j = 19 + idx % 13;
        long gn = base + node;
        if (gn < n) ys[gn * 32 + j] = __half(0.f);
    }
}

__global__ void agg24h_pool_kernel(const __half* __restrict__ ys, const int2* __restrict__ begend,
                                   const unsigned short* __restrict__ csr16, const float* __restrict__ dinv,
                                   const int* __restrict__ batch, float* __restrict__ pool, int n) {
    int node = (int)(((long)blockIdx.x * blockDim.x + threadIdx.x) >> 6);
    int lane = threadIdx.x & 63;
    if (node >= n) return;
    int grp = lane >> 4, f = lane & 15;
    int2 be = begend[node];
    int beg = be.x, end = be.y;
    float2 acc = {0.f, 0.f};
    int eb = beg;
    for (; eb + 32 <= end; eb += 32) {
        int s[8]; unsigned int u[8];
#pragma unroll
        for (int j = 0; j < 8; ++j) s[j] = csr16[eb + grp + 4 * j];
#pragma unroll
        for (int j = 0; j < 8; ++j) u[j] = ((const unsigned int*)ys)[(long)s[j] * 16 + f];
#pragma unroll
        for (int j = 0; j < 8; ++j) {
            float2 v = __half22float2(*(__half2*)&u[j]);
            acc.x += v.x; acc.y += v.y;
        }
    }
    if (eb + 16 <= end) {
        int s[4]; unsigned int u[4];
#pragma unroll
        for (int j = 0; j < 4; ++j) s[j] = csr16[eb + grp + 4 * j];
#pragma unroll
        for (int j = 0; j < 4; ++j) u[j] = ((const unsigned int*)ys)[(long)s[j] * 16 + f];
#pragma unroll
        for (int j = 0; j < 4; ++j) {
            float2 v = __half22float2(*(__half2*)&u[j]);
            acc.x += v.x; acc.y += v.y;
        }
        eb += 16;
    }
    for (int e = eb + grp; e < end; e += 4) {
        unsigned int u = ((const unsigned int*)ys)[(long)csr16[e] * 16 + f];
        float2 v = __half22float2(*(__half2*)&u);
        acc.x += v.x; acc.y += v.y;
    }
    acc.x += __shfl_down(acc.x, 32);
    acc.y += __shfl_down(acc.y, 32);
    acc.x += __shfl_down(acc.x, 16);
    acc.y += __shfl_down(acc.y, 16);
    if (lane < 16) {
        int g = batch[node];
        float sc = dinv[node];
        int c0 = 2 * f;
        if (c0 < NCLS) atomicAdd(&pool[(long)g * 24 + c0], acc.x * sc);
        if (c0 + 1 < NCLS) atomicAdd(&pool[(long)g * 24 + c0 + 1], acc.y * sc);
    }
}

__global__ void final_kernel(const float* __restrict__ pool, const float* __restrict__ cnt,
                             const float* __restrict__ b3l, const float* __restrict__ bl,
                             float* __restrict__ out, int G) {
    int i = blockIdx.x * blockDim.x + threadIdx.x;
    if (i >= G * NCLS) return;
    int g = i / NCLS, j = i % NCLS;
    float c = cnt[g];
    out[i] = (c > 0.f) ? pool[(long)g * 24 + j] / c + b3l[j] + bl[j] : bl[j];
}

// ---------------- launch ----------------

static inline size_t align256(size_t x) { return (x + 255) & ~(size_t)255; }

extern "C" void kernel_launch(void* const* d_in, const int* in_sizes, int n_in,
                              void* d_out, int out_size, void* d_ws, size_t ws_size,
                              hipStream_t stream) {
    const float* x    = (const float*)d_in[0];
    const int*   ei   = (const int*)d_in[1];
    const int*   batch= (const int*)d_in[2];
    const float* W1   = (const float*)d_in[3];
    const float* b1   = (const float*)d_in[4];
    const float* W2   = (const float*)d_in[5];
    const float* b2   = (const float*)d_in[6];
    const float* W3   = (const float*)d_in[7];
    const float* b3   = (const float*)d_in[8];
    const float* Wl   = (const float*)d_in[9];
    const float* bl   = (const float*)d_in[10];
    float* out = (float*)d_out;

    const int N = in_sizes[0] / F_IN;
    const int E = in_sizes[1] / 2;
    const int G = out_size / NCLS;
    const int* src = ei;
    const int* dst = ei + E;
    const int nSB = (E + EPB - 1) / EPB;
    const int nBK = (N + RNODES - 1) / RNODES;
    // cap: mean edges per USED bucket = E*RNODES/N; +768 (~12 sigma) slack
    int cap = (int)((long long)E * RNODES / N) + 768;
    if (cap + RNODES > OUTL_CAP) cap = OUTL_CAP - RNODES;
    const int rst = cap + RNODES;

    // workspace carve-up
    char* p = (char*)d_ws;
    size_t off = 0;
    unsigned int*   bents  = (unsigned int*)(p + off);   off = align256(off + (size_t)NB * cap * 4);
    unsigned short* csr16  = (unsigned short*)(p + off); off = align256(off + (size_t)NB * rst * 2);
    int2*           begend = (int2*)(p + off);           off = align256(off + (size_t)N * 8);
    float*          dinv   = (float*)(p + off);          off = align256(off + (size_t)N * 4);
    __half*         x16h   = (__half*)(p + off);         off = align256(off + (size_t)N * 16 * 2);
    __half*         h1h    = (__half*)(p + off);         off = align256(off + (size_t)N * HIDDEN * 2);
    __half*         hsh    = (__half*)(p + off);         off = align256(off + (size_t)N * HIDDEN * 2);
    __half*         h2h    = (__half*)(p + off);         off = align256(off + (size_t)N * HIDDEN * 2);
    __half*         y32h   = (__half*)(p + off);         off = align256(off + (size_t)N * 32 * 2);
    __half*         W2Th   = (__half*)(p + off);         off = align256(off + (size_t)HIDDEN * HIDDEN * 2);
    float*          W3l    = (float*)(p + off);          off = align256(off + (size_t)HIDDEN * NCLS * 4);
    float*          b3l    = (float*)(p + off);          off = align256(off + (size_t)NCLS * 4);
    float*          pool   = (float*)(p + off);
    float*          gcnt   = pool + (size_t)G * 24;
    int*            bcur   = (int*)(pool + (size_t)G * 25);  // adjacent: one memset covers all
    off = align256(off + (size_t)G * 25 * 4 + NB * 4);
    (void)ws_size; (void)n_in;

    // one memset zeroes pool, gcnt, and bcur
    hipMemsetAsync(pool, 0, (size_t)G * 25 * 4 + NB * 4, stream);

    // CSR build (scatter includes w3l + W2 fp16 conversion as extra blocks)
    scatter_kernel<<<nSB + 15, 256, 0, stream>>>(src, dst, bcur, bents, E, cap, nSB,
                                                 W3, Wl, b3, W3l, b3l, W2, W2Th);
    build_kernel<<<nBK, 512, 0, stream>>>(bents, bcur, x, batch, begend, csr16,
                                          dinv, gcnt, x16h, N, cap, rst);

    const int aggBlocks = (N + 3) / 4;  // 4 waves/block, wave per node

    // layer 1 fused: h1 = relu((dinv*sum x16h)@W1 + b1) -> fp16
    agg16_gemm_kernel<<<aggBlocks, 256, 0, stream>>>(x16h, begend, csr16, dinv, W1, b1, h1h, N);

    // layer 2: hsh = half((h1@W2)*dinv) row-major [MFMA] ; h2h = relu(dinv*sum + b2) fp16
    gemm_mfma_kernel<<<(N + 63) / 64, 256, 0, stream>>>(h1h, W2Th, dinv, hsh, N);
    agg128h_kernel<<<aggBlocks, 256, 0, stream>>>(hsh, begend, csr16, dinv, b2, h2h, N);

    // folded layer 3 + pool
    gemm_y32h_kernel<<<(N + 11) / 12, 256, 0, stream>>>(h2h, W3l, dinv, y32h, N);
    agg24h_pool_kernel<<<aggBlocks, 256, 0, stream>>>(y32h, begend, csr16, dinv, batch, pool, N);
    final_kernel<<<(G * NCLS + 255) / 256, 256, 0, stream>>>(pool, gcnt, b3l, bl, out, G);
}